// Round 2
// baseline (1159.622 us; speedup 1.0000x reference)
//
#include <hip/hip_runtime.h>
#include <stdint.h>

#define B_ROWS 4096
#define D_DIM  1024
#define E_NUM  8
#define C_DIM  4096
#define LOSS_COEF 0.01f
#define EPS_COMBINE 2.220446049250313e-16f

typedef float  f32x4  __attribute__((ext_vector_type(4)));
typedef __bf16 bf16x8 __attribute__((ext_vector_type(8)));

// RNE float -> bf16 bits (values here are tame; no NaN handling needed)
static __device__ __forceinline__ unsigned short f2bf(float f) {
    unsigned int u = __float_as_uint(f);
    u += 0x7fffu + ((u >> 16) & 1u);
    return (unsigned short)(u >> 16);
}

// async global->LDS, 16B per lane; LDS dest = wave-uniform base + lane*16
static __device__ __forceinline__ void async16(const void* g, void* l) {
    __builtin_amdgcn_global_load_lds(
        (const __attribute__((address_space(1))) unsigned int*)g,
        (__attribute__((address_space(3))) unsigned int*)l, 16, 0, 0);
}

#define NT_BLOCKS ((C_DIM / 64) * (D_DIM / 64) * E_NUM) // 8192 transpose blocks

// Fused prep: blocks [0, NT_BLOCKS) transpose w_exp fp32 [8][1024][4096] ->
// wT bf16 [8][4096][1024] (k-contiguous); blocks [NT_BLOCKS, +1024) do the
// gating (logits, top-4 softmax, gates, stats atomics, xb emission). Gating
// has no dependency on the transpose, so its blocks hide in the tail.
__global__ __launch_bounds__(256) void prep_kernel(
    const float* __restrict__ x,
    const float* __restrict__ wg,
    const float* __restrict__ wexp,
    unsigned short* __restrict__ xb,
    unsigned short* __restrict__ wT,
    float* __restrict__ gates,
    float* __restrict__ stats)
{
    const int t = threadIdx.x;
    if ((int)blockIdx.x < NT_BLOCKS) {
        __shared__ float T[64][68];           // pad 68: conflict-free col reads
        __shared__ unsigned short W[64][72];  // pad 72: 16B-aligned, even banks
        const int bid = blockIdx.x;
        const int e  = bid >> 10;             // 64 c-tiles * 16 k-tiles
        const int k0 = ((bid >> 6) & 15) * 64;
        const int c0 = (bid & 63) * 64;
        const float* src = wexp + ((size_t)e * D_DIM + k0) * C_DIM + c0;
        #pragma unroll
        for (int i = 0; i < 4; ++i) {
            int kr = i * 16 + (t >> 4);
            int cg = (t & 15) * 4;
            *(float4*)&T[kr][cg] = *(const float4*)(src + (size_t)kr * C_DIM + cg);
        }
        __syncthreads();
        {
            const int c  = t & 63;
            const int kq = (t >> 6) * 16;
            unsigned short h[16];
            #pragma unroll
            for (int j = 0; j < 16; ++j) h[j] = f2bf(T[kq + j][c]);
            *(uint4*)&W[c][kq]     = ((const uint4*)h)[0];
            *(uint4*)&W[c][kq + 8] = ((const uint4*)h)[1];
        }
        __syncthreads();
        unsigned short* dstb = wT + (size_t)e * C_DIM * D_DIM;
        #pragma unroll
        for (int r = 0; r < 2; ++r) {
            int i  = r * 256 + t;
            int c3 = i >> 3;
            int k8 = (i & 7) * 8;
            *(uint4*)(dstb + (size_t)(c0 + c3) * D_DIM + k0 + k8) = *(const uint4*)&W[c3][k8];
        }
    } else {
        __shared__ float simp[E_NUM], sload[E_NUM];
        if (t < E_NUM) { simp[t] = 0.0f; sload[t] = 0.0f; }
        __syncthreads();
        const int lane = t & 63;
        const int wid  = t >> 6;
        const int row  = ((int)blockIdx.x - NT_BLOCKS) * 4 + wid;

        float acc[8] = {0.f,0.f,0.f,0.f,0.f,0.f,0.f,0.f};
        #pragma unroll
        for (int i = 0; i < 4; ++i) {
            int d = i * 256 + lane * 4;
            float4 xv = *(const float4*)(x + (size_t)row * D_DIM + d);
            unsigned short hh[4] = { f2bf(xv.x), f2bf(xv.y), f2bf(xv.z), f2bf(xv.w) };
            *(uint2*)(xb + (size_t)row * D_DIM + d) = *(const uint2*)hh;
            float xa[4] = { xv.x, xv.y, xv.z, xv.w };
            #pragma unroll
            for (int j = 0; j < 4; ++j) {
                const float4* wp = (const float4*)(wg + (size_t)(d + j) * 8);
                float4 w0 = wp[0], w1 = wp[1];
                acc[0] += xa[j] * w0.x; acc[1] += xa[j] * w0.y;
                acc[2] += xa[j] * w0.z; acc[3] += xa[j] * w0.w;
                acc[4] += xa[j] * w1.x; acc[5] += xa[j] * w1.y;
                acc[6] += xa[j] * w1.z; acc[7] += xa[j] * w1.w;
            }
        }
        #pragma unroll
        for (int off = 32; off > 0; off >>= 1)
            #pragma unroll
            for (int e = 0; e < 8; ++e)
                acc[e] += __shfl_xor(acc[e], off, 64);
        if (lane == 0) {
            float val[4]; int idx[4]; unsigned used = 0;
            #pragma unroll
            for (int j = 0; j < 4; ++j) {       // strict > : lowest index wins ties
                float best = -1e30f; int bi = 0;
                for (int ee = 0; ee < 8; ++ee)
                    if (!(used & (1u << ee)) && acc[ee] > best) { best = acc[ee]; bi = ee; }
                used |= 1u << bi; val[j] = best; idx[j] = bi;
            }
            float mx = val[0], sum = 0.f, gv[4];
            #pragma unroll
            for (int j = 0; j < 4; ++j) { gv[j] = __expf(val[j] - mx); sum += gv[j]; }
            float inv = 1.0f / sum;
            float gout[8] = {0.f,0.f,0.f,0.f,0.f,0.f,0.f,0.f};
            #pragma unroll
            for (int j = 0; j < 4; ++j) gout[idx[j]] = gv[j] * inv;
            #pragma unroll
            for (int e = 0; e < 8; ++e) gates[(size_t)row * 8 + e] = gout[e];
            #pragma unroll
            for (int j = 0; j < 4; ++j) {
                atomicAdd(&simp[idx[j]], gv[j] * inv);
                atomicAdd(&sload[idx[j]], 1.0f);
            }
        }
        __syncthreads();
        if (t < E_NUM) {
            atomicAdd(&stats[t],          simp[t]);
            atomicAdd(&stats[E_NUM + t],  sload[t]);
        }
    }
}

// Fused dense MoE. Tile 128 rows x 64 cols, 4 waves (2x2), each wave 64x32 x
// 2 experts per pass (4 passes). LDS layout is LINEAR per fragment (round-1
// win: bank conflicts 3.4e7 -> ~0): A stored as [16-row group][k-chunk][row]
// so every ds_read_b128 is base + lane*16, matching the global_load_lds
// write order. NEW: 3-deep circular staging pipeline with counted vmcnt —
// stages for steps s, s+1, s+2 in flight; each step waits vmcnt(4) ("oldest
// stage complete, next still flying") + raw s_barrier. Never drains to 0 in
// the main loop (T3/T4). Re-staging buf[(s+2)%3] after barrier(s) is safe:
// that buffer was last read in step s-1, and every wave's reads retired
// (lgkmcnt before its MFMAs) before it reached barrier(s).
__global__ __launch_bounds__(256, 3) void moe_main_kernel(
    const unsigned short* __restrict__ xb,   // bf16 bits [4096][1024]
    const unsigned short* __restrict__ wT,   // bf16 bits [8][4096][1024]
    const float* __restrict__ bexp,          // [8][4096]
    const float* __restrict__ gates,         // [4096][8]
    const float* __restrict__ stats,         // [16] (complete after prep)
    float* __restrict__ out)                 // [4096][4096] (+ loss at end)
{
    __shared__ unsigned short As[3][4096];   // 3 bufs x 8KB
    __shared__ unsigned short Bs[3][4096];   // 3 bufs x 8KB
    __shared__ float gs[128 * 8];            // gates tile (no pad: reads are
                                             // broadcast across ln=0..15)
    // total LDS = 24576+24576+4096 = 53248 B -> 3 blocks/CU

    const int tid  = threadIdx.x;
    const int lane = tid & 63;
    const int wid  = tid >> 6;     // 0..3
    const int wm   = wid >> 1;     // 2x2 wave grid: 64 rows x 32 cols each
    const int wn   = wid & 1;
    const int q    = lane >> 4;
    const int ln   = lane & 15;

    // XCD-aware swizzle (T1): 2048 blocks, 8 XCDs, 2048%8==0 -> bijective.
    // Each XCD gets 256 consecutive original ids = 8 col-panels of B reuse.
    const int bid  = blockIdx.x;
    const int swz  = (bid & 7) * 256 + (bid >> 3);
    const int row0 = (swz & 31) * 128;
    const int col0 = (swz >> 5) * 64;

    // loss (stats are final: prep kernel completed before this launch)
    if (bid == 0 && tid == 0) {
        float mi = 0.f, ml = 0.f;
        for (int e = 0; e < 8; ++e) { mi += stats[e]; ml += stats[8 + e]; }
        mi *= 0.125f; ml *= 0.125f;
        float vi = 0.f, vl = 0.f;
        for (int e = 0; e < 8; ++e) {
            float a = stats[e] - mi;     vi += a * a;
            float b = stats[8 + e] - ml; vl += b * b;
        }
        vi *= (1.0f / 7.0f); vl *= (1.0f / 7.0f);
        out[(size_t)B_ROWS * C_DIM] =
            (vi / (mi * mi + 1e-10f) + vl / (ml * ml + 1e-10f)) * LOSS_COEF;
    }

    #pragma unroll
    for (int i = 0; i < 4; ++i) {
        int idx = i * 256 + tid;
        gs[idx] = gates[(size_t)row0 * 8 + idx];
    }
    // bias tile in registers: 16 floats/thread (col = col0+wn*32+fn*16+ln)
    float bv[8][2];
    #pragma unroll
    for (int eG = 0; eG < 8; ++eG)
        #pragma unroll
        for (int fn = 0; fn < 2; ++fn)
            bv[eG][fn] = bexp[(size_t)eG * C_DIM + col0 + wn * 32 + fn * 16 + ln];

    // Staging geometry: wave w, lane l stages row (w*16 + (l&15)), k-chunk
    // (l>>4) to LDS slot base + l*16 -> LDS holds [group][chunk][row].
    // Lanes {r,16+r,32+r,48+r} read one contiguous 64B row segment, so
    // global coalescing is unchanged.
    const int sr = tid & 15;
    const int sq = (tid >> 4) & 3;
    const unsigned short* gA = xb + (size_t)(row0 + wid * 16 + sr) * D_DIM + sq * 8;
    const int be = wid >> 1;                          // expert within pair
    const unsigned short* gB = wT + (size_t)be * C_DIM * D_DIM
                             + (size_t)(col0 + (wid & 1) * 32 + sr) * D_DIM + sq * 8;

    char* const aBase = (char*)As + wid * 1024;       // wave-uniform; HW adds lane*16
    char* const bBase = (char*)Bs + be * 4096 + (wid & 1) * 2048;

    auto stage = [&](int s) {
        const int bf = s - (s / 3) * 3;               // s % 3
        const int ko = (s & 31) << 5;                 // k offset (shorts)
        const size_t eo = (size_t)((s >> 5) * 2) * C_DIM * D_DIM;
        char* a = aBase + bf * 8192;
        char* b = bBase + bf * 8192;
        async16(gA + ko,                    a);       // A rows 0-63
        async16(gA + ko + 64 * D_DIM,       a + 4096);// A rows 64-127
        async16(gB + eo + ko,               b);       // B cols +0..15
        async16(gB + eo + ko + 16 * D_DIM,  b + 1024);// B cols +16..31
    };

    const f32x4 vzero = {0.f, 0.f, 0.f, 0.f};
    f32x4 comb[4][2];
    #pragma unroll
    for (int i = 0; i < 4; ++i)
        #pragma unroll
        for (int j = 0; j < 2; ++j) comb[i][j] = vzero;

    // fence: all pre-pipeline loads (gs, bv) issued & retired before staging,
    // so in-loop vmcnt counts track only stage() ops.
    asm volatile("s_waitcnt vmcnt(0)" ::: "memory");
    stage(0);
    stage(1);

    #pragma unroll
    for (int eg = 0; eg < 4; ++eg) {
        f32x4 acc[4][2][2];                  // [fm][fn][expert]
        #pragma unroll
        for (int i = 0; i < 4; ++i)
            #pragma unroll
            for (int j = 0; j < 2; ++j)
                #pragma unroll
                for (int e = 0; e < 2; ++e) acc[i][j][e] = vzero;

        for (int kt = 0; kt < 32; ++kt) {
            const int s = eg * 32 + kt;
            // counted wait: stage(s) done, stage(s+1) still in flight
            if (eg == 3 && kt == 31) asm volatile("s_waitcnt vmcnt(0)" ::: "memory");
            else                     asm volatile("s_waitcnt vmcnt(4)" ::: "memory");
            __builtin_amdgcn_s_barrier();
            asm volatile("" ::: "memory");
            __builtin_amdgcn_sched_barrier(0);   // keep ds_reads below barrier

            if (s < 126) stage(s + 2);           // refill buf[(s+2)%3]

            const int bf = s - (s / 3) * 3;
            const unsigned short* pa = (const unsigned short*)((const char*)As + bf * 8192);
            const unsigned short* pb = (const unsigned short*)((const char*)Bs + bf * 8192);
            bf16x8 af[4], bfr[2][2];
            #pragma unroll
            for (int fm = 0; fm < 4; ++fm)       // linear: base + lane*16 bytes
                af[fm] = *(const bf16x8*)(pa + (wm * 4 + fm) * 512 + lane * 8);
            #pragma unroll
            for (int fn = 0; fn < 2; ++fn)
                #pragma unroll
                for (int e = 0; e < 2; ++e)
                    bfr[fn][e] = *(const bf16x8*)(pb + e * 2048 + (wn * 2 + fn) * 512 + lane * 8);

            #pragma unroll
            for (int fm = 0; fm < 4; ++fm)
                #pragma unroll
                for (int fn = 0; fn < 2; ++fn)
                    #pragma unroll
                    for (int e = 0; e < 2; ++e)
                        acc[fm][fn][e] = __builtin_amdgcn_mfma_f32_16x16x32_bf16(
                            af[fm], bfr[fn][e], acc[fm][fn][e], 0, 0, 0);
            // no trailing barrier: next iteration's counted vmcnt + barrier
            // is the only sync per step
        }

        // epilogue: comb += gate * exp(acc + bias)   (C/D: col=ln, row=q*4+r)
        #pragma unroll
        for (int e = 0; e < 2; ++e) {
            int eG = eg * 2 + e;
            #pragma unroll
            for (int fn = 0; fn < 2; ++fn) {
                float bval = bv[eG][fn];
                #pragma unroll
                for (int fm = 0; fm < 4; ++fm)
                    #pragma unroll
                    for (int r = 0; r < 4; ++r) {
                        float g = gs[(wm * 64 + fm * 16 + q * 4 + r) * 8 + eG];
                        comb[fm][fn][r] += g * __expf(acc[fm][fn][e][r] + bval);
                    }
            }
        }
    }

    #pragma unroll
    for (int fm = 0; fm < 4; ++fm)
        #pragma unroll
        for (int fn = 0; fn < 2; ++fn)
            #pragma unroll
            for (int r = 0; r < 4; ++r) {
                int row = row0 + wm * 64 + fm * 16 + q * 4 + r;
                int col = col0 + wn * 32 + fn * 16 + ln;
                float c = comb[fm][fn][r];
                c = (c == 0.0f) ? EPS_COMBINE : c;
                out[(size_t)row * C_DIM + col] = __logf(c);
            }
}

extern "C" void kernel_launch(void* const* d_in, const int* in_sizes, int n_in,
                              void* d_out, int out_size, void* d_ws, size_t ws_size,
                              hipStream_t stream) {
    const float* x    = (const float*)d_in[0];
    const float* wg   = (const float*)d_in[1];
    const float* wexp = (const float*)d_in[2];
    const float* bexp = (const float*)d_in[3];
    // d_in[4] is k==4 (hard-coded in kernels)
    float* out = (float*)d_out;
    char*  ws  = (char*)d_ws;

    unsigned short* wT    = (unsigned short*)ws;               // 67108864 B
    unsigned short* xb    = (unsigned short*)(ws + 67108864);  // 8388608 B
    float*          gates = (float*)(ws + 75497472);           // 131072 B
    float*          stats = (float*)(ws + 75628544);           // 64 B

    hipMemsetAsync(stats, 0, 16 * sizeof(float), stream);
    prep_kernel<<<NT_BLOCKS + B_ROWS / 4, 256, 0, stream>>>(
        x, wg, wexp, xb, wT, gates, stats);

    moe_main_kernel<<<(B_ROWS / 128) * (C_DIM / 64), 256, 0, stream>>>(
        xb, wT, bexp, gates, stats, out);
}

// Round 3
// 928.600 us; speedup vs baseline: 1.2488x; 1.2488x over previous
//
#include <hip/hip_runtime.h>
#include <stdint.h>

#define B_ROWS 4096
#define D_DIM  1024
#define E_NUM  8
#define C_DIM  4096
#define LOSS_COEF 0.01f
#define EPS_COMBINE 2.220446049250313e-16f

typedef float  f32x4  __attribute__((ext_vector_type(4)));
typedef __bf16 bf16x8 __attribute__((ext_vector_type(8)));

// RNE float -> bf16 bits (values here are tame; no NaN handling needed)
static __device__ __forceinline__ unsigned short f2bf(float f) {
    unsigned int u = __float_as_uint(f);
    u += 0x7fffu + ((u >> 16) & 1u);
    return (unsigned short)(u >> 16);
}

// async global->LDS, 16B per lane; LDS dest = wave-uniform base + lane*16
static __device__ __forceinline__ void async16(const void* g, void* l) {
    __builtin_amdgcn_global_load_lds(
        (const __attribute__((address_space(1))) unsigned int*)g,
        (__attribute__((address_space(3))) unsigned int*)l, 16, 0, 0);
}

#define NT_BLOCKS ((C_DIM / 64) * (D_DIM / 64) * E_NUM) // 8192 transpose blocks

// Fused prep: blocks [0, NT_BLOCKS) transpose w_exp fp32 [8][1024][4096] ->
// wT bf16 [8][4096][1024] (k-contiguous); blocks [NT_BLOCKS, +1024) do the
// gating (logits, top-4 softmax, gates, stats atomics, xb emission). Gating
// has no dependency on the transpose, so its blocks hide in the tail.
__global__ __launch_bounds__(256) void prep_kernel(
    const float* __restrict__ x,
    const float* __restrict__ wg,
    const float* __restrict__ wexp,
    unsigned short* __restrict__ xb,
    unsigned short* __restrict__ wT,
    float* __restrict__ gates,
    float* __restrict__ stats)
{
    const int t = threadIdx.x;
    if ((int)blockIdx.x < NT_BLOCKS) {
        __shared__ float T[64][68];           // pad 68: conflict-free col reads
        __shared__ unsigned short W[64][72];  // pad 72: 16B-aligned, even banks
        const int bid = blockIdx.x;
        const int e  = bid >> 10;             // 64 c-tiles * 16 k-tiles
        const int k0 = ((bid >> 6) & 15) * 64;
        const int c0 = (bid & 63) * 64;
        const float* src = wexp + ((size_t)e * D_DIM + k0) * C_DIM + c0;
        #pragma unroll
        for (int i = 0; i < 4; ++i) {
            int kr = i * 16 + (t >> 4);
            int cg = (t & 15) * 4;
            *(float4*)&T[kr][cg] = *(const float4*)(src + (size_t)kr * C_DIM + cg);
        }
        __syncthreads();
        {
            const int c  = t & 63;
            const int kq = (t >> 6) * 16;
            unsigned short h[16];
            #pragma unroll
            for (int j = 0; j < 16; ++j) h[j] = f2bf(T[kq + j][c]);
            *(uint4*)&W[c][kq]     = ((const uint4*)h)[0];
            *(uint4*)&W[c][kq + 8] = ((const uint4*)h)[1];
        }
        __syncthreads();
        unsigned short* dstb = wT + (size_t)e * C_DIM * D_DIM;
        #pragma unroll
        for (int r = 0; r < 2; ++r) {
            int i  = r * 256 + t;
            int c3 = i >> 3;
            int k8 = (i & 7) * 8;
            *(uint4*)(dstb + (size_t)(c0 + c3) * D_DIM + k0 + k8) = *(const uint4*)&W[c3][k8];
        }
    } else {
        __shared__ float simp[E_NUM], sload[E_NUM];
        if (t < E_NUM) { simp[t] = 0.0f; sload[t] = 0.0f; }
        __syncthreads();
        const int lane = t & 63;
        const int wid  = t >> 6;
        const int row  = ((int)blockIdx.x - NT_BLOCKS) * 4 + wid;

        float acc[8] = {0.f,0.f,0.f,0.f,0.f,0.f,0.f,0.f};
        #pragma unroll
        for (int i = 0; i < 4; ++i) {
            int d = i * 256 + lane * 4;
            float4 xv = *(const float4*)(x + (size_t)row * D_DIM + d);
            unsigned short hh[4] = { f2bf(xv.x), f2bf(xv.y), f2bf(xv.z), f2bf(xv.w) };
            *(uint2*)(xb + (size_t)row * D_DIM + d) = *(const uint2*)hh;
            float xa[4] = { xv.x, xv.y, xv.z, xv.w };
            #pragma unroll
            for (int j = 0; j < 4; ++j) {
                const float4* wp = (const float4*)(wg + (size_t)(d + j) * 8);
                float4 w0 = wp[0], w1 = wp[1];
                acc[0] += xa[j] * w0.x; acc[1] += xa[j] * w0.y;
                acc[2] += xa[j] * w0.z; acc[3] += xa[j] * w0.w;
                acc[4] += xa[j] * w1.x; acc[5] += xa[j] * w1.y;
                acc[6] += xa[j] * w1.z; acc[7] += xa[j] * w1.w;
            }
        }
        #pragma unroll
        for (int off = 32; off > 0; off >>= 1)
            #pragma unroll
            for (int e = 0; e < 8; ++e)
                acc[e] += __shfl_xor(acc[e], off, 64);
        if (lane == 0) {
            float val[4]; int idx[4]; unsigned used = 0;
            #pragma unroll
            for (int j = 0; j < 4; ++j) {       // strict > : lowest index wins ties
                float best = -1e30f; int bi = 0;
                for (int ee = 0; ee < 8; ++ee)
                    if (!(used & (1u << ee)) && acc[ee] > best) { best = acc[ee]; bi = ee; }
                used |= 1u << bi; val[j] = best; idx[j] = bi;
            }
            float mx = val[0], sum = 0.f, gv[4];
            #pragma unroll
            for (int j = 0; j < 4; ++j) { gv[j] = __expf(val[j] - mx); sum += gv[j]; }
            float inv = 1.0f / sum;
            float gout[8] = {0.f,0.f,0.f,0.f,0.f,0.f,0.f,0.f};
            #pragma unroll
            for (int j = 0; j < 4; ++j) gout[idx[j]] = gv[j] * inv;
            #pragma unroll
            for (int e = 0; e < 8; ++e) gates[(size_t)row * 8 + e] = gout[e];
            #pragma unroll
            for (int j = 0; j < 4; ++j) {
                atomicAdd(&simp[idx[j]], gv[j] * inv);
                atomicAdd(&sload[idx[j]], 1.0f);
            }
        }
        __syncthreads();
        if (t < E_NUM) {
            atomicAdd(&stats[t],          simp[t]);
            atomicAdd(&stats[E_NUM + t],  sload[t]);
        }
    }
}

// Fused dense MoE. Tile 128 rows x 64 cols, 4 waves (2x2), each wave 64x32 x
// 2 experts per pass (4 passes). Schedule = the proven round-0 structure:
// per k-step {4x async16; __syncthreads; ds_read+16 MFMA; __syncthreads},
// single-buffered. ONLY the LDS layout differs from round 0: linear
// [group][chunk][row] so every ds_read_b128 is base + lane*16 — identical
// order to the global_load_lds write side, PMC-verified conflict-free
// (round 1: SQ_LDS_BANK_CONFLICT 3.4e7 -> 0). Plus XCD swizzle (T1): with
// this schedule the load latency is exposed at the first barrier, so
// L3->L2 hit conversion directly shrinks the stall.
__global__ __launch_bounds__(256, 3) void moe_main_kernel(
    const unsigned short* __restrict__ xb,   // bf16 bits [4096][1024]
    const unsigned short* __restrict__ wT,   // bf16 bits [8][4096][1024]
    const float* __restrict__ bexp,          // [8][4096]
    const float* __restrict__ gates,         // [4096][8]
    const float* __restrict__ stats,         // [16] (complete after prep)
    float* __restrict__ out)                 // [4096][4096] (+ loss at end)
{
    __shared__ unsigned short As[4096];      // 8KB: [8 grp][4 chunk][16 row][8]
    __shared__ unsigned short Bs[4096];      // 8KB: [2 e][2 h][2 cp][4 chunk][16 col][8]
    __shared__ float gs[128 * 8];            // gates tile (broadcast reads)
    // total LDS = 8192 + 8192 + 4096 = 20480 B

    const int tid  = threadIdx.x;
    const int lane = tid & 63;
    const int wid  = tid >> 6;     // 0..3
    const int wm   = wid >> 1;     // 2x2 wave grid: 64 rows x 32 cols each
    const int wn   = wid & 1;
    const int q    = lane >> 4;
    const int ln   = lane & 15;

    // XCD-aware swizzle (T1): 2048 blocks, 8 XCDs, 2048%8==0 -> bijective.
    // XCD x gets contiguous range [x*256, x*256+256) = 8 full B col-panels.
    const int bid  = blockIdx.x;
    const int swz  = (bid & 7) * 256 + (bid >> 3);
    const int row0 = (swz & 31) * 128;
    const int col0 = (swz >> 5) * 64;

    // loss (stats are final: prep kernel completed before this launch)
    if (bid == 0 && tid == 0) {
        float mi = 0.f, ml = 0.f;
        for (int e = 0; e < 8; ++e) { mi += stats[e]; ml += stats[8 + e]; }
        mi *= 0.125f; ml *= 0.125f;
        float vi = 0.f, vl = 0.f;
        for (int e = 0; e < 8; ++e) {
            float a = stats[e] - mi;     vi += a * a;
            float b = stats[8 + e] - ml; vl += b * b;
        }
        vi *= (1.0f / 7.0f); vl *= (1.0f / 7.0f);
        out[(size_t)B_ROWS * C_DIM] =
            (vi / (mi * mi + 1e-10f) + vl / (ml * ml + 1e-10f)) * LOSS_COEF;
    }

    #pragma unroll
    for (int i = 0; i < 4; ++i) {
        int idx = i * 256 + tid;
        gs[idx] = gates[(size_t)row0 * 8 + idx];
    }
    // bias tile in registers: 16 floats/thread (col = col0+wn*32+fn*16+ln)
    float bv[8][2];
    #pragma unroll
    for (int eG = 0; eG < 8; ++eG)
        #pragma unroll
        for (int fn = 0; fn < 2; ++fn)
            bv[eG][fn] = bexp[(size_t)eG * C_DIM + col0 + wn * 32 + fn * 16 + ln];

    // Staging geometry: wave w, lane l = sq*16+sr stages row (w*16 + sr),
    // k-chunk sq, to LDS slot base + l*16 -> layout [group][chunk][row][8].
    // Lanes {sr, 16+sr, 32+sr, 48+sr} cover one contiguous 64B row segment,
    // so global coalescing matches the row-linear order.
    const int sr = tid & 15;
    const int sq = (tid >> 4) & 3;
    const unsigned short* gA = xb + (size_t)(row0 + wid * 16 + sr) * D_DIM + sq * 8;
    const int be = wid >> 1;                          // expert within pair
    const unsigned short* gB = wT + (size_t)be * C_DIM * D_DIM
                             + (size_t)(col0 + (wid & 1) * 32 + sr) * D_DIM + sq * 8;

    char* const ldsA = (char*)As + wid * 1024;        // wave-uniform; HW adds lane*16
    char* const ldsB = (char*)Bs + be * 4096 + (wid & 1) * 2048;

    const f32x4 vzero = {0.f, 0.f, 0.f, 0.f};
    f32x4 comb[4][2];
    #pragma unroll
    for (int i = 0; i < 4; ++i)
        #pragma unroll
        for (int j = 0; j < 2; ++j) comb[i][j] = vzero;

    for (int eg = 0; eg < 4; ++eg) {
        f32x4 acc[4][2][2];                  // [fm][fn][expert]
        #pragma unroll
        for (int i = 0; i < 4; ++i)
            #pragma unroll
            for (int j = 0; j < 2; ++j)
                #pragma unroll
                for (int e = 0; e < 2; ++e) acc[i][j][e] = vzero;

        const size_t eo = (size_t)(eg * 2) * C_DIM * D_DIM;

        for (int kt = 0; kt < D_DIM / 32; ++kt) {
            const int ko = kt * 32;
            async16(gA + ko,                   ldsA);          // A rows 0-63
            async16(gA + ko + 64 * D_DIM,      ldsA + 4096);   // A rows 64-127
            async16(gB + eo + ko,              ldsB);          // B cols +0..15
            async16(gB + eo + ko + 16 * D_DIM, ldsB + 1024);   // B cols +16..31

            __syncthreads();

            bf16x8 af[4], bfr[2][2];
            #pragma unroll
            for (int fm = 0; fm < 4; ++fm)       // linear: base + lane*16 bytes
                af[fm] = *(const bf16x8*)(As + (wm * 4 + fm) * 512 + lane * 8);
            #pragma unroll
            for (int fn = 0; fn < 2; ++fn)
                #pragma unroll
                for (int e = 0; e < 2; ++e)
                    bfr[fn][e] = *(const bf16x8*)(Bs + e * 2048 +
                                    (wn * 2 + fn) * 512 + lane * 8);

            #pragma unroll
            for (int fm = 0; fm < 4; ++fm)
                #pragma unroll
                for (int fn = 0; fn < 2; ++fn)
                    #pragma unroll
                    for (int e = 0; e < 2; ++e)
                        acc[fm][fn][e] = __builtin_amdgcn_mfma_f32_16x16x32_bf16(
                            af[fm], bfr[fn][e], acc[fm][fn][e], 0, 0, 0);

            __syncthreads();
        }

        // epilogue: comb += gate * exp(acc + bias)   (C/D: col=ln, row=q*4+r)
        #pragma unroll
        for (int e = 0; e < 2; ++e) {
            int eG = eg * 2 + e;
            #pragma unroll
            for (int fn = 0; fn < 2; ++fn) {
                float bval = bv[eG][fn];
                #pragma unroll
                for (int fm = 0; fm < 4; ++fm)
                    #pragma unroll
                    for (int r = 0; r < 4; ++r) {
                        float g = gs[(wm * 64 + fm * 16 + q * 4 + r) * 8 + eG];
                        comb[fm][fn][r] += g * __expf(acc[fm][fn][e][r] + bval);
                    }
            }
        }
    }

    #pragma unroll
    for (int fm = 0; fm < 4; ++fm)
        #pragma unroll
        for (int fn = 0; fn < 2; ++fn)
            #pragma unroll
            for (int r = 0; r < 4; ++r) {
                int row = row0 + wm * 64 + fm * 16 + q * 4 + r;
                int col = col0 + wn * 32 + fn * 16 + ln;
                float c = comb[fm][fn][r];
                c = (c == 0.0f) ? EPS_COMBINE : c;
                out[(size_t)row * C_DIM + col] = __logf(c);
            }
}

extern "C" void kernel_launch(void* const* d_in, const int* in_sizes, int n_in,
                              void* d_out, int out_size, void* d_ws, size_t ws_size,
                              hipStream_t stream) {
    const float* x    = (const float*)d_in[0];
    const float* wg   = (const float*)d_in[1];
    const float* wexp = (const float*)d_in[2];
    const float* bexp = (const float*)d_in[3];
    // d_in[4] is k==4 (hard-coded in kernels)
    float* out = (float*)d_out;
    char*  ws  = (char*)d_ws;

    unsigned short* wT    = (unsigned short*)ws;               // 67108864 B
    unsigned short* xb    = (unsigned short*)(ws + 67108864);  // 8388608 B
    float*          gates = (float*)(ws + 75497472);           // 131072 B
    float*          stats = (float*)(ws + 75628544);           // 64 B

    hipMemsetAsync(stats, 0, 16 * sizeof(float), stream);
    prep_kernel<<<NT_BLOCKS + B_ROWS / 4, 256, 0, stream>>>(
        x, wg, wexp, xb, wT, gates, stats);

    moe_main_kernel<<<(B_ROWS / 128) * (C_DIM / 64), 256, 0, stream>>>(
        xb, wT, bexp, gates, stats, out);
}

// Round 4
// 722.314 us; speedup vs baseline: 1.6054x; 1.2856x over previous
//
#include <hip/hip_runtime.h>
#include <stdint.h>

#define B_ROWS 4096
#define D_DIM  1024
#define E_NUM  8
#define C_DIM  4096
#define LOSS_COEF 0.01f
#define EPS_COMBINE 2.220446049250313e-16f

typedef float  f32x4  __attribute__((ext_vector_type(4)));
typedef __bf16 bf16x8 __attribute__((ext_vector_type(8)));

// RNE float -> bf16 bits (values here are tame; no NaN handling needed)
static __device__ __forceinline__ unsigned short f2bf(float f) {
    unsigned int u = __float_as_uint(f);
    u += 0x7fffu + ((u >> 16) & 1u);
    return (unsigned short)(u >> 16);
}

// async global->LDS, 16B per lane; LDS dest = wave-uniform base + lane*16
static __device__ __forceinline__ void async16(const void* g, void* l) {
    __builtin_amdgcn_global_load_lds(
        (const __attribute__((address_space(1))) unsigned int*)g,
        (__attribute__((address_space(3))) unsigned int*)l, 16, 0, 0);
}

#define NT_BLOCKS ((C_DIM / 64) * (D_DIM / 64) * E_NUM) // 8192 transpose blocks

// Fused prep: blocks [0, NT_BLOCKS) transpose w_exp fp32 [8][1024][4096] ->
// wT bf16 [8][4096][1024] (k-contiguous); blocks [NT_BLOCKS, +1024) do the
// gating (logits, top-4 softmax, gates, stats atomics, xb emission). Gating
// has no dependency on the transpose, so its blocks hide in the tail.
__global__ __launch_bounds__(256) void prep_kernel(
    const float* __restrict__ x,
    const float* __restrict__ wg,
    const float* __restrict__ wexp,
    unsigned short* __restrict__ xb,
    unsigned short* __restrict__ wT,
    float* __restrict__ gates,
    float* __restrict__ stats)
{
    const int t = threadIdx.x;
    if ((int)blockIdx.x < NT_BLOCKS) {
        __shared__ float T[64][68];           // pad 68: conflict-free col reads
        __shared__ unsigned short W[64][72];  // pad 72: 16B-aligned, even banks
        const int bid = blockIdx.x;
        const int e  = bid >> 10;             // 64 c-tiles * 16 k-tiles
        const int k0 = ((bid >> 6) & 15) * 64;
        const int c0 = (bid & 63) * 64;
        const float* src = wexp + ((size_t)e * D_DIM + k0) * C_DIM + c0;
        #pragma unroll
        for (int i = 0; i < 4; ++i) {
            int kr = i * 16 + (t >> 4);
            int cg = (t & 15) * 4;
            *(float4*)&T[kr][cg] = *(const float4*)(src + (size_t)kr * C_DIM + cg);
        }
        __syncthreads();
        {
            const int c  = t & 63;
            const int kq = (t >> 6) * 16;
            unsigned short h[16];
            #pragma unroll
            for (int j = 0; j < 16; ++j) h[j] = f2bf(T[kq + j][c]);
            *(uint4*)&W[c][kq]     = ((const uint4*)h)[0];
            *(uint4*)&W[c][kq + 8] = ((const uint4*)h)[1];
        }
        __syncthreads();
        unsigned short* dstb = wT + (size_t)e * C_DIM * D_DIM;
        #pragma unroll
        for (int r = 0; r < 2; ++r) {
            int i  = r * 256 + t;
            int c3 = i >> 3;
            int k8 = (i & 7) * 8;
            *(uint4*)(dstb + (size_t)(c0 + c3) * D_DIM + k0 + k8) = *(const uint4*)&W[c3][k8];
        }
    } else {
        __shared__ float simp[E_NUM], sload[E_NUM];
        if (t < E_NUM) { simp[t] = 0.0f; sload[t] = 0.0f; }
        __syncthreads();
        const int lane = t & 63;
        const int wid  = t >> 6;
        const int row  = ((int)blockIdx.x - NT_BLOCKS) * 4 + wid;

        float acc[8] = {0.f,0.f,0.f,0.f,0.f,0.f,0.f,0.f};
        #pragma unroll
        for (int i = 0; i < 4; ++i) {
            int d = i * 256 + lane * 4;
            float4 xv = *(const float4*)(x + (size_t)row * D_DIM + d);
            unsigned short hh[4] = { f2bf(xv.x), f2bf(xv.y), f2bf(xv.z), f2bf(xv.w) };
            *(uint2*)(xb + (size_t)row * D_DIM + d) = *(const uint2*)hh;
            float xa[4] = { xv.x, xv.y, xv.z, xv.w };
            #pragma unroll
            for (int j = 0; j < 4; ++j) {
                const float4* wp = (const float4*)(wg + (size_t)(d + j) * 8);
                float4 w0 = wp[0], w1 = wp[1];
                acc[0] += xa[j] * w0.x; acc[1] += xa[j] * w0.y;
                acc[2] += xa[j] * w0.z; acc[3] += xa[j] * w0.w;
                acc[4] += xa[j] * w1.x; acc[5] += xa[j] * w1.y;
                acc[6] += xa[j] * w1.z; acc[7] += xa[j] * w1.w;
            }
        }
        #pragma unroll
        for (int off = 32; off > 0; off >>= 1)
            #pragma unroll
            for (int e = 0; e < 8; ++e)
                acc[e] += __shfl_xor(acc[e], off, 64);
        if (lane == 0) {
            float val[4]; int idx[4]; unsigned used = 0;
            #pragma unroll
            for (int j = 0; j < 4; ++j) {       // strict > : lowest index wins ties
                float best = -1e30f; int bi = 0;
                for (int ee = 0; ee < 8; ++ee)
                    if (!(used & (1u << ee)) && acc[ee] > best) { best = acc[ee]; bi = ee; }
                used |= 1u << bi; val[j] = best; idx[j] = bi;
            }
            float mx = val[0], sum = 0.f, gv[4];
            #pragma unroll
            for (int j = 0; j < 4; ++j) { gv[j] = __expf(val[j] - mx); sum += gv[j]; }
            float inv = 1.0f / sum;
            float gout[8] = {0.f,0.f,0.f,0.f,0.f,0.f,0.f,0.f};
            #pragma unroll
            for (int j = 0; j < 4; ++j) gout[idx[j]] = gv[j] * inv;
            #pragma unroll
            for (int e = 0; e < 8; ++e) gates[(size_t)row * 8 + e] = gout[e];
            #pragma unroll
            for (int j = 0; j < 4; ++j) {
                atomicAdd(&simp[idx[j]], gv[j] * inv);
                atomicAdd(&sload[idx[j]], 1.0f);
            }
        }
        __syncthreads();
        if (t < E_NUM) {
            atomicAdd(&stats[t],          simp[t]);
            atomicAdd(&stats[E_NUM + t],  sload[t]);
        }
    }
}

__global__ void loss_kernel(const float* __restrict__ stats, float* __restrict__ out_loss) {
    if (threadIdx.x == 0) {
        float mi = 0.f, ml = 0.f;
        for (int e = 0; e < 8; ++e) { mi += stats[e]; ml += stats[8 + e]; }
        mi *= 0.125f; ml *= 0.125f;
        float vi = 0.f, vl = 0.f;
        for (int e = 0; e < 8; ++e) {
            float a = stats[e] - mi;     vi += a * a;
            float b = stats[8 + e] - ml; vl += b * b;
        }
        vi *= (1.0f / 7.0f); vl *= (1.0f / 7.0f);
        out_loss[0] = (vi / (mi * mi + 1e-10f) + vl / (ml * ml + 1e-10f)) * LOSS_COEF;
    }
}

// Fused dense MoE. Tile 128 rows x 64 cols, 4 waves (2x2), each wave 64x32 x
// 2 experts per pass (4 passes). Schedule + register structure = the proven
// round-0 kernel EXACTLY (bias in LDS bs, gates in LDS gs padded x9, no
// extra always-live registers — r2/r3 showed +16 VGPR crosses the spill
// cliff at launch_bounds(256,3): WRITE_SIZE 66->576 MB). ONLY delta vs r0:
// LDS layout is linear [group][chunk][row], so every ds_read_b128 is
// base + lane*16 — identical order to the global_load_lds write side.
// PMC-verified conflict-free (SQ_LDS_BANK_CONFLICT 3.4e7 -> 0 in r1/r3).
__global__ __launch_bounds__(256, 3) void moe_main_kernel(
    const unsigned short* __restrict__ xb,   // bf16 bits [4096][1024]
    const unsigned short* __restrict__ wT,   // bf16 bits [8][4096][1024]
    const float* __restrict__ bexp,          // [8][4096]
    const float* __restrict__ gates,         // [4096][8]
    float* __restrict__ out)                 // [4096][4096]
{
    __shared__ unsigned short As[4096];      // 8KB: [8 grp][4 chunk][16 row][8]
    __shared__ unsigned short Bs[4096];      // 8KB: [2 e][2 half][4 chunk][16 col][8]
    __shared__ float gs[128 * 9];            // gates tile (pad 9: epilogue
                                             // reads stride 36 words -> no conflict)
    __shared__ float bs[8 * 64];             // bias tile
    // total LDS = 8192 + 8192 + 4608 + 2048 = 23040 B (same as r0)

    const int tid  = threadIdx.x;
    const int lane = tid & 63;
    const int wid  = tid >> 6;     // 0..3
    const int wm   = wid >> 1;     // 2x2 wave grid: 64 rows x 32 cols each
    const int wn   = wid & 1;
    const int q    = lane >> 4;
    const int ln   = lane & 15;
    const int row0 = blockIdx.x * 128;
    const int col0 = blockIdx.y * 64;

    #pragma unroll
    for (int i = 0; i < 4; ++i) {
        int idx = i * 256 + tid;
        gs[(idx >> 3) * 9 + (idx & 7)] = gates[(size_t)row0 * 8 + idx];
    }
    {
        int e = tid >> 5, c = tid & 31;
        bs[e * 64 + c]      = bexp[(size_t)e * C_DIM + col0 + c];
        bs[e * 64 + c + 32] = bexp[(size_t)e * C_DIM + col0 + c + 32];
    }

    // Staging geometry: wave w, lane l stages row (w*16 + (l&15)), k-chunk
    // (l>>4), to LDS slot base + l*16 -> layout [group][chunk][row][8].
    // Lanes {sr, 16+sr, 32+sr, 48+sr} cover one contiguous 64B row segment,
    // so global coalescing matches the row-linear order.
    const int sr = tid & 15;
    const int sq = (tid >> 4) & 3;
    const unsigned short* gA = xb + (size_t)(row0 + wid * 16 + sr) * D_DIM + sq * 8;
    const int be = wid >> 1;                          // expert within pair
    const unsigned short* gB = wT + (size_t)be * C_DIM * D_DIM
                             + (size_t)(col0 + (wid & 1) * 32 + sr) * D_DIM + sq * 8;

    char* const ldsA = (char*)As + wid * 1024;        // wave-uniform; HW adds lane*16
    char* const ldsB = (char*)Bs + be * 4096 + (wid & 1) * 2048;

    const f32x4 vzero = {0.f, 0.f, 0.f, 0.f};
    f32x4 comb[4][2];
    #pragma unroll
    for (int i = 0; i < 4; ++i)
        #pragma unroll
        for (int j = 0; j < 2; ++j) comb[i][j] = vzero;

    for (int eg = 0; eg < 4; ++eg) {
        f32x4 acc[4][2][2];                  // [fm][fn][expert]
        #pragma unroll
        for (int i = 0; i < 4; ++i)
            #pragma unroll
            for (int j = 0; j < 2; ++j)
                #pragma unroll
                for (int e = 0; e < 2; ++e) acc[i][j][e] = vzero;

        const size_t eo = (size_t)(eg * 2) * C_DIM * D_DIM;

        for (int kt = 0; kt < D_DIM / 32; ++kt) {
            const int ko = kt * 32;
            async16(gA + ko,                   ldsA);          // A rows 0-63
            async16(gA + ko + 64 * D_DIM,      ldsA + 4096);   // A rows 64-127
            async16(gB + eo + ko,              ldsB);          // B cols +0..15
            async16(gB + eo + ko + 16 * D_DIM, ldsB + 1024);   // B cols +16..31

            __syncthreads();

            bf16x8 af[4], bfr[2][2];
            #pragma unroll
            for (int fm = 0; fm < 4; ++fm)       // linear: base + lane*16 bytes
                af[fm] = *(const bf16x8*)(As + (wm * 4 + fm) * 512 + lane * 8);
            #pragma unroll
            for (int fn = 0; fn < 2; ++fn)
                #pragma unroll
                for (int e = 0; e < 2; ++e)
                    bfr[fn][e] = *(const bf16x8*)(Bs + e * 2048 +
                                    (wn * 2 + fn) * 512 + lane * 8);

            #pragma unroll
            for (int fm = 0; fm < 4; ++fm)
                #pragma unroll
                for (int fn = 0; fn < 2; ++fn)
                    #pragma unroll
                    for (int e = 0; e < 2; ++e)
                        acc[fm][fn][e] = __builtin_amdgcn_mfma_f32_16x16x32_bf16(
                            af[fm], bfr[fn][e], acc[fm][fn][e], 0, 0, 0);

            __syncthreads();
        }

        // epilogue: comb += gate * exp(acc + bias)   (C/D: col=ln, row=q*4+r)
        #pragma unroll
        for (int e = 0; e < 2; ++e) {
            int eG = eg * 2 + e;
            #pragma unroll
            for (int fn = 0; fn < 2; ++fn) {
                float bval = bs[eG * 64 + wn * 32 + fn * 16 + ln];
                #pragma unroll
                for (int fm = 0; fm < 4; ++fm)
                    #pragma unroll
                    for (int r = 0; r < 4; ++r) {
                        float g = gs[(wm * 64 + fm * 16 + q * 4 + r) * 9 + eG];
                        comb[fm][fn][r] += g * __expf(acc[fm][fn][e][r] + bval);
                    }
            }
        }
    }

    #pragma unroll
    for (int fm = 0; fm < 4; ++fm)
        #pragma unroll
        for (int fn = 0; fn < 2; ++fn)
            #pragma unroll
            for (int r = 0; r < 4; ++r) {
                int row = row0 + wm * 64 + fm * 16 + q * 4 + r;
                int col = col0 + wn * 32 + fn * 16 + ln;
                float c = comb[fm][fn][r];
                c = (c == 0.0f) ? EPS_COMBINE : c;
                out[(size_t)row * C_DIM + col] = __logf(c);
            }
}

extern "C" void kernel_launch(void* const* d_in, const int* in_sizes, int n_in,
                              void* d_out, int out_size, void* d_ws, size_t ws_size,
                              hipStream_t stream) {
    const float* x    = (const float*)d_in[0];
    const float* wg   = (const float*)d_in[1];
    const float* wexp = (const float*)d_in[2];
    const float* bexp = (const float*)d_in[3];
    // d_in[4] is k==4 (hard-coded in kernels)
    float* out = (float*)d_out;
    char*  ws  = (char*)d_ws;

    unsigned short* wT    = (unsigned short*)ws;               // 67108864 B
    unsigned short* xb    = (unsigned short*)(ws + 67108864);  // 8388608 B
    float*          gates = (float*)(ws + 75497472);           // 131072 B
    float*          stats = (float*)(ws + 75628544);           // 64 B

    hipMemsetAsync(stats, 0, 16 * sizeof(float), stream);
    prep_kernel<<<NT_BLOCKS + B_ROWS / 4, 256, 0, stream>>>(
        x, wg, wexp, xb, wT, gates, stats);
    loss_kernel<<<1, 64, 0, stream>>>(stats, out + (size_t)B_ROWS * C_DIM);

    dim3 grid(B_ROWS / 128, C_DIM / 64);
    moe_main_kernel<<<grid, 256, 0, stream>>>(xb, wT, bexp, gates, out);
}

// Round 5
// 572.451 us; speedup vs baseline: 2.0257x; 1.2618x over previous
//
#include <hip/hip_runtime.h>
#include <stdint.h>

#define B_ROWS 4096
#define D_DIM  1024
#define E_NUM  8
#define C_DIM  4096
#define LOSS_COEF 0.01f
#define EPS_COMBINE 2.220446049250313e-16f

typedef float  f32x4  __attribute__((ext_vector_type(4)));
typedef __bf16 bf16x8 __attribute__((ext_vector_type(8)));

// RNE float -> bf16 bits (values here are tame; no NaN handling needed)
static __device__ __forceinline__ unsigned short f2bf(float f) {
    unsigned int u = __float_as_uint(f);
    u += 0x7fffu + ((u >> 16) & 1u);
    return (unsigned short)(u >> 16);
}

// async global->LDS, 16B per lane; LDS dest = wave-uniform base + lane*16
static __device__ __forceinline__ void async16(const void* g, void* l) {
    __builtin_amdgcn_global_load_lds(
        (const __attribute__((address_space(1))) unsigned int*)g,
        (__attribute__((address_space(3))) unsigned int*)l, 16, 0, 0);
}

#define NT_BLOCKS ((C_DIM / 64) * (D_DIM / 64) * E_NUM) // 8192 transpose blocks

// Fused prep: blocks [0, NT_BLOCKS) transpose w_exp fp32 [8][1024][4096] ->
// wT bf16 [8][4096][1024] (k-contiguous); blocks [NT_BLOCKS, +1024) do the
// gating (logits, top-4 softmax, gates, stats atomics, xb emission). Gating
// has no dependency on the transpose, so its blocks hide in the tail.
__global__ __launch_bounds__(256) void prep_kernel(
    const float* __restrict__ x,
    const float* __restrict__ wg,
    const float* __restrict__ wexp,
    unsigned short* __restrict__ xb,
    unsigned short* __restrict__ wT,
    float* __restrict__ gates,
    float* __restrict__ stats)
{
    const int t = threadIdx.x;
    if ((int)blockIdx.x < NT_BLOCKS) {
        __shared__ float T[64][68];           // pad 68: conflict-free col reads
        __shared__ unsigned short W[64][72];  // pad 72: 16B-aligned, even banks
        const int bid = blockIdx.x;
        const int e  = bid >> 10;             // 64 c-tiles * 16 k-tiles
        const int k0 = ((bid >> 6) & 15) * 64;
        const int c0 = (bid & 63) * 64;
        const float* src = wexp + ((size_t)e * D_DIM + k0) * C_DIM + c0;
        #pragma unroll
        for (int i = 0; i < 4; ++i) {
            int kr = i * 16 + (t >> 4);
            int cg = (t & 15) * 4;
            *(float4*)&T[kr][cg] = *(const float4*)(src + (size_t)kr * C_DIM + cg);
        }
        __syncthreads();
        {
            const int c  = t & 63;
            const int kq = (t >> 6) * 16;
            unsigned short h[16];
            #pragma unroll
            for (int j = 0; j < 16; ++j) h[j] = f2bf(T[kq + j][c]);
            *(uint4*)&W[c][kq]     = ((const uint4*)h)[0];
            *(uint4*)&W[c][kq + 8] = ((const uint4*)h)[1];
        }
        __syncthreads();
        unsigned short* dstb = wT + (size_t)e * C_DIM * D_DIM;
        #pragma unroll
        for (int r = 0; r < 2; ++r) {
            int i  = r * 256 + t;
            int c3 = i >> 3;
            int k8 = (i & 7) * 8;
            *(uint4*)(dstb + (size_t)(c0 + c3) * D_DIM + k0 + k8) = *(const uint4*)&W[c3][k8];
        }
    } else {
        __shared__ float simp[E_NUM], sload[E_NUM];
        if (t < E_NUM) { simp[t] = 0.0f; sload[t] = 0.0f; }
        __syncthreads();
        const int lane = t & 63;
        const int wid  = t >> 6;
        const int row  = ((int)blockIdx.x - NT_BLOCKS) * 4 + wid;

        float acc[8] = {0.f,0.f,0.f,0.f,0.f,0.f,0.f,0.f};
        #pragma unroll
        for (int i = 0; i < 4; ++i) {
            int d = i * 256 + lane * 4;
            float4 xv = *(const float4*)(x + (size_t)row * D_DIM + d);
            unsigned short hh[4] = { f2bf(xv.x), f2bf(xv.y), f2bf(xv.z), f2bf(xv.w) };
            *(uint2*)(xb + (size_t)row * D_DIM + d) = *(const uint2*)hh;
            float xa[4] = { xv.x, xv.y, xv.z, xv.w };
            #pragma unroll
            for (int j = 0; j < 4; ++j) {
                const float4* wp = (const float4*)(wg + (size_t)(d + j) * 8);
                float4 w0 = wp[0], w1 = wp[1];
                acc[0] += xa[j] * w0.x; acc[1] += xa[j] * w0.y;
                acc[2] += xa[j] * w0.z; acc[3] += xa[j] * w0.w;
                acc[4] += xa[j] * w1.x; acc[5] += xa[j] * w1.y;
                acc[6] += xa[j] * w1.z; acc[7] += xa[j] * w1.w;
            }
        }
        #pragma unroll
        for (int off = 32; off > 0; off >>= 1)
            #pragma unroll
            for (int e = 0; e < 8; ++e)
                acc[e] += __shfl_xor(acc[e], off, 64);
        if (lane == 0) {
            float val[4]; int idx[4]; unsigned used = 0;
            #pragma unroll
            for (int j = 0; j < 4; ++j) {       // strict > : lowest index wins ties
                float best = -1e30f; int bi = 0;
                for (int ee = 0; ee < 8; ++ee)
                    if (!(used & (1u << ee)) && acc[ee] > best) { best = acc[ee]; bi = ee; }
                used |= 1u << bi; val[j] = best; idx[j] = bi;
            }
            float mx = val[0], sum = 0.f, gv[4];
            #pragma unroll
            for (int j = 0; j < 4; ++j) { gv[j] = __expf(val[j] - mx); sum += gv[j]; }
            float inv = 1.0f / sum;
            float gout[8] = {0.f,0.f,0.f,0.f,0.f,0.f,0.f,0.f};
            #pragma unroll
            for (int j = 0; j < 4; ++j) gout[idx[j]] = gv[j] * inv;
            #pragma unroll
            for (int e = 0; e < 8; ++e) gates[(size_t)row * 8 + e] = gout[e];
            #pragma unroll
            for (int j = 0; j < 4; ++j) {
                atomicAdd(&simp[idx[j]], gv[j] * inv);
                atomicAdd(&sload[idx[j]], 1.0f);
            }
        }
        __syncthreads();
        if (t < E_NUM) {
            atomicAdd(&stats[t],          simp[t]);
            atomicAdd(&stats[E_NUM + t],  sload[t]);
        }
    }
}

__global__ void loss_kernel(const float* __restrict__ stats, float* __restrict__ out_loss) {
    if (threadIdx.x == 0) {
        float mi = 0.f, ml = 0.f;
        for (int e = 0; e < 8; ++e) { mi += stats[e]; ml += stats[8 + e]; }
        mi *= 0.125f; ml *= 0.125f;
        float vi = 0.f, vl = 0.f;
        for (int e = 0; e < 8; ++e) {
            float a = stats[e] - mi;     vi += a * a;
            float b = stats[8 + e] - ml; vl += b * b;
        }
        vi *= (1.0f / 7.0f); vl *= (1.0f / 7.0f);
        out_loss[0] = (vi / (mi * mi + 1e-10f) + vl / (ml * ml + 1e-10f)) * LOSS_COEF;
    }
}

// Fused dense MoE. Tile 128 rows x 64 cols, 4 waves (2x2), each wave 64x32 x
// 2 experts per pass (4 passes). Addressing/register structure = round-0
// PROVEN kernel verbatim: XOR-swizzled quad-contiguous global gather
// (qg = (tid&3)^(rS&3)) + XOR-compensated fragment reads (fq). r1/r4 showed
// the "conflict-free" linear alternative forces a strided lane gather that
// is +165us (request-rate bound); the XOR layout's 3.4e7 conflict-cycles
// (~+4cy/read, separate LDS pipe) are cheaper. Bias/gates live in LDS —
// +16 always-live VGPR crosses the spill cliff at launch_bounds(256,3)
// (r2/r3: WRITE_SIZE 66->576MB). ONLY delta vs r0: double-buffered LDS,
// ONE barrier per k-step, prefetch of step s+1 issued before compute of
// step s — the barrier's vmcnt(0) drain lands after ~200cy of ds_read+MFMA
// instead of immediately after issue, and barrier count halves (256->128).
__global__ __launch_bounds__(256, 3) void moe_main_kernel(
    const unsigned short* __restrict__ xb,   // bf16 bits [4096][1024]
    const unsigned short* __restrict__ wT,   // bf16 bits [8][4096][1024]
    const float* __restrict__ bexp,          // [8][4096]
    const float* __restrict__ gates,         // [4096][8]
    float* __restrict__ out)                 // [4096][4096]
{
    __shared__ unsigned short As[2][4096];   // dbuf x 8KB [m][k-chunk swizzled]
    __shared__ unsigned short Bs[2][4096];   // dbuf x 8KB [e][n][k-chunk swizzled]
    __shared__ float gs[128 * 9];            // gates tile (pad 9)
    __shared__ float bs[8 * 64];             // bias tile
    // total LDS = 16384 + 16384 + 4608 + 2048 = 39424 B -> 3 blocks/CU

    const int tid  = threadIdx.x;
    const int lane = tid & 63;
    const int wid  = tid >> 6;     // 0..3
    const int wm   = wid >> 1;     // 2x2 wave grid: 64 rows x 32 cols each
    const int wn   = wid & 1;
    const int q    = lane >> 4;
    const int ln   = lane & 15;
    const int row0 = blockIdx.x * 128;
    const int col0 = blockIdx.y * 64;

    #pragma unroll
    for (int i = 0; i < 4; ++i) {
        int idx = i * 256 + tid;
        gs[(idx >> 3) * 9 + (idx & 7)] = gates[(size_t)row0 * 8 + idx];
    }
    {
        int e = tid >> 5, c = tid & 31;
        bs[e * 64 + c]      = bexp[(size_t)e * C_DIM + col0 + c];
        bs[e * 64 + c + 32] = bexp[(size_t)e * C_DIM + col0 + c + 32];
    }

    // staging: thread t -> LDS slot (row = t>>2, qs = t&3), source chunk
    // qg = qs ^ (row&3) (XOR swizzle); fragment reads use chunk q^(ln&3).
    // Quad-contiguous gather: lanes 4r..4r+3 cover one 64B row segment.
    const int rS = tid >> 2;                 // A row 0..63(+64) / B col 0..63
    const int qg = (tid & 3) ^ (rS & 3);
    const unsigned short* gA  = xb + (size_t)(row0 + rS) * D_DIM + qg * 8;
    const unsigned short* gBb = wT + (size_t)(col0 + rS) * D_DIM + qg * 8;

    const int fq = ((q ^ (ln & 3)) << 3);    // swizzled fragment chunk (shorts)

    // stage step s into buffer db: A rows 0-63 / 64-127, B experts 2*(s>>5), +1
    auto stage = [&](int s, int db) {
        const int ko = (s & 31) << 5;                       // k offset (shorts)
        const size_t eo = (size_t)((s >> 5) * 2) * C_DIM * D_DIM;
        char* a = (char*)As + db * 8192 + wid * 1024;       // wave-uniform base
        char* b = (char*)Bs + db * 8192 + wid * 1024;
        async16(gA + ko,                        a);         // A rows 0-63
        async16(gA + ko + 64 * D_DIM,           a + 4096);  // A rows 64-127
        async16(gBb + eo + ko,                  b);         // B expert 2eg
        async16(gBb + eo + C_DIM * D_DIM + ko,  b + 4096);  // B expert 2eg+1
    };

    const f32x4 vzero = {0.f, 0.f, 0.f, 0.f};
    f32x4 comb[4][2];
    #pragma unroll
    for (int i = 0; i < 4; ++i)
        #pragma unroll
        for (int j = 0; j < 2; ++j) comb[i][j] = vzero;

    int buf = 0;
    stage(0, 0);
    __syncthreads();                          // drains vmcnt(0): buf0 ready

    for (int eg = 0; eg < 4; ++eg) {
        f32x4 acc[4][2][2];                  // [fm][fn][expert]
        #pragma unroll
        for (int i = 0; i < 4; ++i)
            #pragma unroll
            for (int j = 0; j < 2; ++j)
                #pragma unroll
                for (int e = 0; e < 2; ++e) acc[i][j][e] = vzero;

        for (int kt = 0; kt < 32; ++kt) {
            const int s = eg * 32 + kt;
            if (s < 127) stage(s + 1, buf ^ 1);   // prefetch (crosses eg)

            const unsigned short* pa = &As[buf][0];
            const unsigned short* pb = &Bs[buf][0];
            bf16x8 af[4], bfr[2][2];
            #pragma unroll
            for (int fm = 0; fm < 4; ++fm)
                af[fm] = *(const bf16x8*)(pa + (wm * 64 + fm * 16 + ln) * 32 + fq);
            #pragma unroll
            for (int fn = 0; fn < 2; ++fn)
                #pragma unroll
                for (int e = 0; e < 2; ++e)
                    bfr[fn][e] = *(const bf16x8*)(pb + e * 2048 +
                                    (wn * 32 + fn * 16 + ln) * 32 + fq);
            #pragma unroll
            for (int fm = 0; fm < 4; ++fm)
                #pragma unroll
                for (int fn = 0; fn < 2; ++fn)
                    #pragma unroll
                    for (int e = 0; e < 2; ++e)
                        acc[fm][fn][e] = __builtin_amdgcn_mfma_f32_16x16x32_bf16(
                            af[fm], bfr[fn][e], acc[fm][fn][e], 0, 0, 0);

            __syncthreads();   // drains prefetch AFTER compute; also fences
            buf ^= 1;          // buf reuse (everyone's reads retired above)
        }

        // epilogue: comb += gate * exp(acc + bias)   (C/D: col=ln, row=q*4+r)
        #pragma unroll
        for (int e = 0; e < 2; ++e) {
            int eG = eg * 2 + e;
            #pragma unroll
            for (int fn = 0; fn < 2; ++fn) {
                float bval = bs[eG * 64 + wn * 32 + fn * 16 + ln];
                #pragma unroll
                for (int fm = 0; fm < 4; ++fm)
                    #pragma unroll
                    for (int r = 0; r < 4; ++r) {
                        float g = gs[(wm * 64 + fm * 16 + q * 4 + r) * 9 + eG];
                        comb[fm][fn][r] += g * __expf(acc[fm][fn][e][r] + bval);
                    }
            }
        }
    }

    #pragma unroll
    for (int fm = 0; fm < 4; ++fm)
        #pragma unroll
        for (int fn = 0; fn < 2; ++fn)
            #pragma unroll
            for (int r = 0; r < 4; ++r) {
                int row = row0 + wm * 64 + fm * 16 + q * 4 + r;
                int col = col0 + wn * 32 + fn * 16 + ln;
                float c = comb[fm][fn][r];
                c = (c == 0.0f) ? EPS_COMBINE : c;
                out[(size_t)row * C_DIM + col] = __logf(c);
            }
}

extern "C" void kernel_launch(void* const* d_in, const int* in_sizes, int n_in,
                              void* d_out, int out_size, void* d_ws, size_t ws_size,
                              hipStream_t stream) {
    const float* x    = (const float*)d_in[0];
    const float* wg   = (const float*)d_in[1];
    const float* wexp = (const float*)d_in[2];
    const float* bexp = (const float*)d_in[3];
    // d_in[4] is k==4 (hard-coded in kernels)
    float* out = (float*)d_out;
    char*  ws  = (char*)d_ws;

    unsigned short* wT    = (unsigned short*)ws;               // 67108864 B
    unsigned short* xb    = (unsigned short*)(ws + 67108864);  // 8388608 B
    float*          gates = (float*)(ws + 75497472);           // 131072 B
    float*          stats = (float*)(ws + 75628544);           // 64 B

    hipMemsetAsync(stats, 0, 16 * sizeof(float), stream);
    prep_kernel<<<NT_BLOCKS + B_ROWS / 4, 256, 0, stream>>>(
        x, wg, wexp, xb, wT, gates, stats);
    loss_kernel<<<1, 64, 0, stream>>>(stats, out + (size_t)B_ROWS * C_DIM);

    dim3 grid(B_ROWS / 128, C_DIM / 64);
    moe_main_kernel<<<grid, 256, 0, stream>>>(xb, wT, bexp, gates, out);
}

// Round 7
// 558.752 us; speedup vs baseline: 2.0754x; 1.0245x over previous
//
#include <hip/hip_runtime.h>
#include <stdint.h>

#define B_ROWS 4096
#define D_DIM  1024
#define E_NUM  8
#define C_DIM  4096
#define LOSS_COEF 0.01f
#define EPS_COMBINE 2.220446049250313e-16f

typedef float  f32x4  __attribute__((ext_vector_type(4)));
typedef __bf16 bf16x8 __attribute__((ext_vector_type(8)));

// RNE float -> bf16 bits (values here are tame; no NaN handling needed)
static __device__ __forceinline__ unsigned short f2bf(float f) {
    unsigned int u = __float_as_uint(f);
    u += 0x7fffu + ((u >> 16) & 1u);
    return (unsigned short)(u >> 16);
}

// async global->LDS, 16B per lane; LDS dest = wave-uniform base + lane*16
static __device__ __forceinline__ void async16(const void* g, void* l) {
    __builtin_amdgcn_global_load_lds(
        (const __attribute__((address_space(1))) unsigned int*)g,
        (__attribute__((address_space(3))) unsigned int*)l, 16, 0, 0);
}

#define TP_BLOCKS (8 * 8 * 32)   // 2048 transpose blocks (128x128 tiles)

// Fused prep: blocks [0, TP_BLOCKS) transpose w_exp fp32 [8][1024][4096] ->
// wT bf16 [8][4096][1024] (k-contiguous) using 128x128 tiles: 512B read
// granules, 256B write granules (the old 64x64 tiles gave 256B/128B —
// theory: HBM granule fragmentation is why prep ran at ~1.1 TB/s).
// XOR-swizzled bf16 LDS tile (32KB): g' = g ^ ((k>>4)<<1) spreads the
// phase-2 column-gather (8 lanes share c, kch 0..7) across 8 banks while
// keeping phase-1 vector writes conflict-free. Padding is unusable here:
// odd row strides break 8B LDS write alignment.
// Blocks [TP_BLOCKS, +1024) do the gating (unchanged, verified r1-r5).
__global__ __launch_bounds__(256) void prep_kernel(
    const float* __restrict__ x,
    const float* __restrict__ wg,
    const float* __restrict__ wexp,
    unsigned short* __restrict__ xb,
    unsigned short* __restrict__ wT,
    float* __restrict__ gates,
    float* __restrict__ stats)
{
    const int t = threadIdx.x;
    if ((int)blockIdx.x < TP_BLOCKS) {
        __shared__ unsigned short Tt[128 * 128];   // 32KB, swizzled [k][g']
        const int bid = blockIdx.x;
        const int ct = bid & 31;          // c-tile fastest: adjacent blocks
        const int kt = (bid >> 5) & 7;    //   read adjacent 512B chunks
        const int e  = bid >> 8;
        const int k0 = kt * 128, c0 = ct * 128;
        const float* src = wexp + ((size_t)e * D_DIM + k0) * C_DIM + c0;

        // phase 1: load 128 rows x 512B (fp32), convert, swizzled LDS store
        #pragma unroll
        for (int i = 0; i < 16; ++i) {
            const int kr = i * 8 + (t >> 5);          // row in tile
            const int g  = t & 31;                    // 4-col group
            float4 v = *(const float4*)(src + (size_t)kr * C_DIM + g * 4);
            unsigned short h[4] = { f2bf(v.x), f2bf(v.y), f2bf(v.z), f2bf(v.w) };
            const int gp = g ^ (((kr >> 4) & 7) << 1);
            *(uint2*)&Tt[kr * 128 + gp * 4] = *(const uint2*)h;
        }
        __syncthreads();

        // phase 2: per task (c, kch): gather 16 k's for column c, write 32B.
        // 8-lane groups share c with kch 0..7 -> 256B contiguous per c-row.
        unsigned short* dst = wT + (size_t)e * C_DIM * D_DIM
                            + (size_t)c0 * D_DIM + k0;
        #pragma unroll
        for (int i = 0; i < 4; ++i) {
            const int task = i * 256 + t;
            const int kch  = task & 7;
            const int c    = task >> 3;               // 0..127
            const int g    = c >> 2;
            unsigned short hh[16];
            #pragma unroll
            for (int j = 0; j < 16; ++j) {
                const int k  = kch * 16 + j;
                const int gp = g ^ (((k >> 4) & 7) << 1);
                hh[j] = Tt[k * 128 + gp * 4 + (c & 3)];
            }
            *(uint4*)(dst + (size_t)c * D_DIM + kch * 16)     = ((const uint4*)hh)[0];
            *(uint4*)(dst + (size_t)c * D_DIM + kch * 16 + 8) = ((const uint4*)hh)[1];
        }
    } else {
        __shared__ float simp[E_NUM], sload[E_NUM];
        if (t < E_NUM) { simp[t] = 0.0f; sload[t] = 0.0f; }
        __syncthreads();
        const int lane = t & 63;
        const int wid  = t >> 6;
        const int row  = ((int)blockIdx.x - TP_BLOCKS) * 4 + wid;

        float acc[8] = {0.f,0.f,0.f,0.f,0.f,0.f,0.f,0.f};
        #pragma unroll
        for (int i = 0; i < 4; ++i) {
            int d = i * 256 + lane * 4;
            float4 xv = *(const float4*)(x + (size_t)row * D_DIM + d);
            unsigned short hh[4] = { f2bf(xv.x), f2bf(xv.y), f2bf(xv.z), f2bf(xv.w) };
            *(uint2*)(xb + (size_t)row * D_DIM + d) = *(const uint2*)hh;
            float xa[4] = { xv.x, xv.y, xv.z, xv.w };
            #pragma unroll
            for (int j = 0; j < 4; ++j) {
                const float4* wp = (const float4*)(wg + (size_t)(d + j) * 8);
                float4 w0 = wp[0], w1 = wp[1];
                acc[0] += xa[j] * w0.x; acc[1] += xa[j] * w0.y;
                acc[2] += xa[j] * w0.z; acc[3] += xa[j] * w0.w;
                acc[4] += xa[j] * w1.x; acc[5] += xa[j] * w1.y;
                acc[6] += xa[j] * w1.z; acc[7] += xa[j] * w1.w;
            }
        }
        #pragma unroll
        for (int off = 32; off > 0; off >>= 1)
            #pragma unroll
            for (int e = 0; e < 8; ++e)
                acc[e] += __shfl_xor(acc[e], off, 64);
        if (lane == 0) {
            float val[4]; int idx[4]; unsigned used = 0;
            #pragma unroll
            for (int j = 0; j < 4; ++j) {       // strict > : lowest index wins ties
                float best = -1e30f; int bi = 0;
                for (int ee = 0; ee < 8; ++ee)
                    if (!(used & (1u << ee)) && acc[ee] > best) { best = acc[ee]; bi = ee; }
                used |= 1u << bi; val[j] = best; idx[j] = bi;
            }
            float mx = val[0], sum = 0.f, gv[4];
            #pragma unroll
            for (int j = 0; j < 4; ++j) { gv[j] = __expf(val[j] - mx); sum += gv[j]; }
            float inv = 1.0f / sum;
            float gout[8] = {0.f,0.f,0.f,0.f,0.f,0.f,0.f,0.f};
            #pragma unroll
            for (int j = 0; j < 4; ++j) gout[idx[j]] = gv[j] * inv;
            #pragma unroll
            for (int e = 0; e < 8; ++e) gates[(size_t)row * 8 + e] = gout[e];
            #pragma unroll
            for (int j = 0; j < 4; ++j) {
                atomicAdd(&simp[idx[j]], gv[j] * inv);
                atomicAdd(&sload[idx[j]], 1.0f);
            }
        }
        __syncthreads();
        if (t < E_NUM) {
            atomicAdd(&stats[t],          simp[t]);
            atomicAdd(&stats[E_NUM + t],  sload[t]);
        }
    }
}

__global__ void loss_kernel(const float* __restrict__ stats, float* __restrict__ out_loss) {
    if (threadIdx.x == 0) {
        float mi = 0.f, ml = 0.f;
        for (int e = 0; e < 8; ++e) { mi += stats[e]; ml += stats[8 + e]; }
        mi *= 0.125f; ml *= 0.125f;
        float vi = 0.f, vl = 0.f;
        for (int e = 0; e < 8; ++e) {
            float a = stats[e] - mi;     vi += a * a;
            float b = stats[8 + e] - ml; vl += b * b;
        }
        vi *= (1.0f / 7.0f); vl *= (1.0f / 7.0f);
        out_loss[0] = (vi / (mi * mi + 1e-10f) + vl / (ml * ml + 1e-10f)) * LOSS_COEF;
    }
}

// Fused dense MoE — FROZEN at the round-0 proven structure (355us, 775 TF
// effective, at the known ceiling for the 128²/2-barrier shape; r1-r5
// variants: linear layout +165us, counted-vmcnt spill, dbuf -13us).
// Tile 128 rows x 64 cols, 4 waves (2x2), each wave 64x32 x 2 experts per
// pass (4 passes). XOR-swizzled quad-contiguous gather + fq-compensated
// fragment reads; bias/gates in LDS (register budget is saturated: +16
// always-live VGPR triggers accumulator spill, r2/r3).
__global__ __launch_bounds__(256, 3) void moe_main_kernel(
    const unsigned short* __restrict__ xb,   // bf16 bits [4096][1024]
    const unsigned short* __restrict__ wT,   // bf16 bits [8][4096][1024]
    const float* __restrict__ bexp,          // [8][4096]
    const float* __restrict__ gates,         // [4096][8]
    float* __restrict__ out)                 // [4096][4096]
{
    __shared__ unsigned short As[128 * 32];      // [m][k-chunk swizzled], 8KB
    __shared__ unsigned short Bs[2 * 64 * 32];   // [e][n][k-chunk swizzled], 8KB
    __shared__ float gs[128 * 9];                // gates tile (pad 9)
    __shared__ float bs[8 * 64];                 // bias tile

    const int tid  = threadIdx.x;
    const int lane = tid & 63;
    const int wid  = tid >> 6;     // 0..3
    const int wm   = wid >> 1;     // 2x2 wave grid: 64 rows x 32 cols each
    const int wn   = wid & 1;
    const int q    = lane >> 4;
    const int ln   = lane & 15;
    const int row0 = blockIdx.x * 128;
    const int col0 = blockIdx.y * 64;

    #pragma unroll
    for (int i = 0; i < 4; ++i) {
        int idx = i * 256 + tid;
        gs[(idx >> 3) * 9 + (idx & 7)] = gates[(size_t)row0 * 8 + idx];
    }
    {
        int e = tid >> 5, c = tid & 31;
        bs[e * 64 + c]      = bexp[(size_t)e * C_DIM + col0 + c];
        bs[e * 64 + c + 32] = bexp[(size_t)e * C_DIM + col0 + c + 32];
    }

    // staging: thread t -> LDS slot (row = t>>2, qs = t&3), source chunk
    // qg = qs ^ (row&3) (XOR swizzle); fragment reads use chunk q^(ln&3).
    const int rS = tid >> 2;                 // A row 0..63(+64) / B col 0..63
    const int qg = (tid & 3) ^ (rS & 3);
    const unsigned short* gA  = xb + (size_t)(row0 + rS) * D_DIM + qg * 8;
    const unsigned short* gBb = wT + (size_t)(col0 + rS) * D_DIM + qg * 8;
    char* ldsA = (char*)As + wid * 1024;     // wave-uniform base; HW adds lane*16
    char* ldsB = (char*)Bs + wid * 1024;

    const int fq = ((q ^ (ln & 3)) << 3);    // swizzled fragment chunk (shorts)

    const f32x4 vzero = {0.f, 0.f, 0.f, 0.f};
    f32x4 comb[4][2];
    #pragma unroll
    for (int i = 0; i < 4; ++i)
        #pragma unroll
        for (int j = 0; j < 2; ++j) comb[i][j] = vzero;

    for (int eg = 0; eg < 4; ++eg) {
        f32x4 acc[4][2][2];                  // [fm][fn][expert]
        #pragma unroll
        for (int i = 0; i < 4; ++i)
            #pragma unroll
            for (int j = 0; j < 2; ++j)
                #pragma unroll
                for (int e = 0; e < 2; ++e) acc[i][j][e] = vzero;

        const unsigned short* gB0 = gBb + (size_t)(2 * eg)     * C_DIM * D_DIM;
        const unsigned short* gB1 = gBb + (size_t)(2 * eg + 1) * C_DIM * D_DIM;

        for (int kt = 0; kt < D_DIM / 32; ++kt) {
            const int ko = kt * 32;
            async16(gA + ko,               ldsA);          // A rows 0-63
            async16(gA + ko + 64 * D_DIM,  ldsA + 4096);   // A rows 64-127
            async16(gB0 + ko,              ldsB);          // B expert 0
            async16(gB1 + ko,              ldsB + 4096);   // B expert 1

            __syncthreads();

            bf16x8 af[4], bfr[2][2];
            #pragma unroll
            for (int fm = 0; fm < 4; ++fm)
                af[fm] = *(const bf16x8*)(As + (wm * 64 + fm * 16 + ln) * 32 + fq);
            #pragma unroll
            for (int fn = 0; fn < 2; ++fn)
                #pragma unroll
                for (int e = 0; e < 2; ++e)
                    bfr[fn][e] = *(const bf16x8*)(Bs + e * 2048 +
                                    (wn * 32 + fn * 16 + ln) * 32 + fq);
            #pragma unroll
            for (int fm = 0; fm < 4; ++fm)
                #pragma unroll
                for (int fn = 0; fn < 2; ++fn)
                    #pragma unroll
                    for (int e = 0; e < 2; ++e)
                        acc[fm][fn][e] = __builtin_amdgcn_mfma_f32_16x16x32_bf16(
                            af[fm], bfr[fn][e], acc[fm][fn][e], 0, 0, 0);

            __syncthreads();
        }

        // epilogue: comb += gate * exp(acc + bias)   (C/D: col=ln, row=q*4+r)
        #pragma unroll
        for (int e = 0; e < 2; ++e) {
            int eG = eg * 2 + e;
            #pragma unroll
            for (int fn = 0; fn < 2; ++fn) {
                float bval = bs[eG * 64 + wn * 32 + fn * 16 + ln];
                #pragma unroll
                for (int fm = 0; fm < 4; ++fm)
                    #pragma unroll
                    for (int r = 0; r < 4; ++r) {
                        float g = gs[(wm * 64 + fm * 16 + q * 4 + r) * 9 + eG];
                        comb[fm][fn][r] += g * __expf(acc[fm][fn][e][r] + bval);
                    }
            }
        }
    }

    #pragma unroll
    for (int fm = 0; fm < 4; ++fm)
        #pragma unroll
        for (int fn = 0; fn < 2; ++fn)
            #pragma unroll
            for (int r = 0; r < 4; ++r) {
                int row = row0 + wm * 64 + fm * 16 + q * 4 + r;
                int col = col0 + wn * 32 + fn * 16 + ln;
                float c = comb[fm][fn][r];
                c = (c == 0.0f) ? EPS_COMBINE : c;
                out[(size_t)row * C_DIM + col] = __logf(c);
            }
}

extern "C" void kernel_launch(void* const* d_in, const int* in_sizes, int n_in,
                              void* d_out, int out_size, void* d_ws, size_t ws_size,
                              hipStream_t stream) {
    const float* x    = (const float*)d_in[0];
    const float* wg   = (const float*)d_in[1];
    const float* wexp = (const float*)d_in[2];
    const float* bexp = (const float*)d_in[3];
    // d_in[4] is k==4 (hard-coded in kernels)
    float* out = (float*)d_out;
    char*  ws  = (char*)d_ws;

    unsigned short* wT    = (unsigned short*)ws;               // 67108864 B
    unsigned short* xb    = (unsigned short*)(ws + 67108864);  // 8388608 B
    float*          gates = (float*)(ws + 75497472);           // 131072 B
    float*          stats = (float*)(ws + 75628544);           // 64 B

    hipMemsetAsync(stats, 0, 16 * sizeof(float), stream);
    prep_kernel<<<TP_BLOCKS + B_ROWS / 4, 256, 0, stream>>>(
        x, wg, wexp, xb, wT, gates, stats);
    loss_kernel<<<1, 64, 0, stream>>>(stats, out + (size_t)B_ROWS * C_DIM);

    dim3 grid(B_ROWS / 128, C_DIM / 64);
    moe_main_kernel<<<grid, 256, 0, stream>>>(xb, wT, bexp, gates, out);
}